// Round 6
// baseline (87.916 us; speedup 1.0000x reference)
//
#include <hip/hip_runtime.h>
#include <math.h>

// WildcatPool2d: x[32,64,64,512] fp32 -> out[32,512] fp32
// out[b,c] = mean(top20 over 4096 spatial) + mean(bottom20 over 4096 spatial)
//
// Round 6: all previous rounds capped at ~3.6 TB/s read BW; common factor was
// strided (non-contiguous) per-block streams. Split into two kernels:
//   K1: block = (b, 512-row slice), reads 1 MB fully CONTIGUOUS via
//       global_load_lds dwordx4 into a double-buffered 64 KB tile
//       (raw s_barrier + counted vmcnt(8), prefetch never drained).
//       Thread = one channel; 16x sort32+bitonic-merge; writes sorted
//       top20/bot20 per (b, rslice, ch) to workspace (coalesced).
//   K2: per (b,ch) merges the 8 row-slice runs (pad to 32 with +-INF),
//       writes mean(top20)+mean(bot20). 21 MB round-trip, ~6 us.
// Fallback to the round-4 single-kernel path if ws_size < 21 MB.

constexpr int CH     = 512;
constexpr int NR     = 4096;
constexpr int K      = 20;
constexpr int RSLICE = 512;            // rows per K1 block
constexpr int TROWS  = 32;             // rows per tile
constexpr int NT     = RSLICE / TROWS; // 16 tiles
constexpr int TFL    = TROWS * CH;     // 16384 floats = 64 KB
constexpr size_t WS_NEED = (size_t)32 * 8 * 40 * CH * sizeof(float);  // ~21 MB

__device__ __forceinline__ void ce_desc(float& a, float& b) {
  float hi = fmaxf(a, b);
  float lo = fminf(a, b);
  a = hi; b = lo;
}
__device__ __forceinline__ void ce_asc(float& a, float& b) {
  float lo = fminf(a, b);
  float hi = fmaxf(a, b);
  a = lo; b = hi;
}

__device__ __forceinline__ void sort32_desc(float* v) {
  #pragma unroll
  for (int k = 2; k <= 32; k <<= 1) {
    #pragma unroll
    for (int j = k >> 1; j > 0; j >>= 1) {
      #pragma unroll
      for (int i = 0; i < 32; ++i) {
        int l = i ^ j;
        if (l > i) {
          if ((i & k) == 0) ce_desc(v[i], v[l]);
          else              ce_asc(v[i], v[l]);
        }
      }
    }
  }
}
__device__ __forceinline__ void clean32_desc(float* v) {
  #pragma unroll
  for (int j = 16; j > 0; j >>= 1) {
    #pragma unroll
    for (int i = 0; i < 32; ++i) {
      int l = i ^ j;
      if (l > i) ce_desc(v[i], v[l]);
    }
  }
}
__device__ __forceinline__ void clean32_asc(float* v) {
  #pragma unroll
  for (int j = 16; j > 0; j >>= 1) {
    #pragma unroll
    for (int i = 0; i < 32; ++i) {
      int l = i ^ j;
      if (l > i) ce_asc(v[i], v[l]);
    }
  }
}
// top desc(32), d desc(32): keep 32 largest of union
__device__ __forceinline__ void merge_top(float* top, const float* d) {
  #pragma unroll
  for (int i = 0; i < 32; ++i) top[i] = fmaxf(top[i], d[31 - i]);
  clean32_desc(top);
}
// bot asc(32), d DESC(32): keep 32 smallest of union
__device__ __forceinline__ void merge_bot_dDesc(float* bot, const float* d) {
  #pragma unroll
  for (int i = 0; i < 32; ++i) bot[i] = fminf(bot[i], d[i]);
  clean32_asc(bot);
}
// bot asc(32), d ASC(32): keep 32 smallest of union
__device__ __forceinline__ void merge_bot_dAsc(float* bot, const float* d) {
  #pragma unroll
  for (int i = 0; i < 32; ++i) bot[i] = fminf(bot[i], d[31 - i]);
  clean32_asc(bot);
}

__device__ __forceinline__ void gload16(const float* g, float* l) {
  __builtin_amdgcn_global_load_lds(
      (const __attribute__((address_space(1))) void*)g,
      (__attribute__((address_space(3))) void*)l,
      16, 0, 0);
}

// ---------------- K1: per-(b, row-slice) partial top20/bot20 ----------------
__global__ __launch_bounds__(512, 1)
void wildcat_part1(const float* __restrict__ x, float* __restrict__ ws) {
  __shared__ float smem[2 * TFL];   // 128 KB, double-buffered 32x512 tile

  const int b    = blockIdx.x >> 3;
  const int rs   = blockIdx.x & 7;
  const int tid  = threadIdx.x;
  const int w    = tid >> 6;
  const int lane = tid & 63;

  const float* src0 = x + ((size_t)b * NR + (size_t)rs * RSLICE) * CH;

  // tile t: block reads 64 KB CONTIGUOUS [t*64KB, (t+1)*64KB).
  // wave w fills LDS floats [w*2048, (w+1)*2048); per instr: 1 KB contiguous.
  // linear dest == row-major [32][512] tile (global offset == LDS offset).
  auto issue = [&](int t) {
    float* dstb = &smem[(t & 1) * TFL + w * 2048];
    const float* g = src0 + (size_t)t * TFL + w * 2048 + lane * 4;
    #pragma unroll
    for (int i = 0; i < 8; ++i)
      gload16(g + i * 256, dstb + i * 256);
  };

  float top[32], bot[32];

  issue(0);
  issue(1);

  #pragma unroll 1
  for (int t = 0; t < NT; ++t) {
    // own 8 loads of tile t done (tile t+1's 8 stay in flight across barrier)
    if (t < NT - 1) asm volatile("s_waitcnt vmcnt(8)" ::: "memory");
    else            asm volatile("s_waitcnt vmcnt(0)" ::: "memory");
    __builtin_amdgcn_s_barrier();          // all waves' tile-t loads done

    const float* tb = &smem[(t & 1) * TFL];
    float v[32];
    #pragma unroll
    for (int r = 0; r < 32; ++r) v[r] = tb[r * CH + tid];  // 2-way bank: free
    asm volatile("s_waitcnt lgkmcnt(0)" ::: "memory");
    __builtin_amdgcn_sched_barrier(0);
    __builtin_amdgcn_s_barrier();          // all threads done reading buf(t&1)
    if (t + 2 < NT) issue(t + 2);          // overwrite buf(t&1)
    __builtin_amdgcn_sched_barrier(0);

    sort32_desc(v);
    if (t == 0) {
      #pragma unroll
      for (int i = 0; i < 32; ++i) { top[i] = v[i]; bot[i] = v[31 - i]; }
    } else {
      merge_top(top, v);
      merge_bot_dDesc(bot, v);
    }
  }

  // ws layout [b][rs][j 0..39][ch]: writes coalesced across tid per j
  float* wsp = ws + (size_t)(b * 8 + rs) * 40 * CH + tid;
  #pragma unroll
  for (int j = 0; j < 20; ++j) wsp[(size_t)j * CH] = top[j];
  #pragma unroll
  for (int j = 0; j < 20; ++j) wsp[(size_t)(20 + j) * CH] = bot[j];
}

// ---------------- K2: merge 8 row-slice runs per (b, ch) ----------------
__global__ __launch_bounds__(256)
void wildcat_part2(const float* __restrict__ ws, float* __restrict__ out) {
  const int g  = blockIdx.x * 256 + threadIdx.x;   // 0..16383
  const int b  = g >> 9;
  const int ch = g & (CH - 1);
  const float* base = ws + (size_t)b * 8 * 40 * CH + ch;

  float top[32], bot[32];
  #pragma unroll
  for (int j = 0; j < 20; ++j) top[j] = base[(size_t)j * CH];
  #pragma unroll
  for (int j = 20; j < 32; ++j) top[j] = -INFINITY;
  #pragma unroll
  for (int j = 0; j < 20; ++j) bot[j] = base[(size_t)(20 + j) * CH];
  #pragma unroll
  for (int j = 20; j < 32; ++j) bot[j] = INFINITY;

  #pragma unroll 1
  for (int rs = 1; rs < 8; ++rs) {
    const float* p = base + (size_t)rs * 40 * CH;
    float d[32];
    #pragma unroll
    for (int j = 0; j < 20; ++j) d[j] = p[(size_t)j * CH];
    #pragma unroll
    for (int j = 20; j < 32; ++j) d[j] = -INFINITY;   // desc run, pad tail
    merge_top(top, d);
    #pragma unroll
    for (int j = 0; j < 20; ++j) d[j] = p[(size_t)(20 + j) * CH];
    #pragma unroll
    for (int j = 20; j < 32; ++j) d[j] = INFINITY;    // asc run, pad tail
    merge_bot_dAsc(bot, d);
  }

  float s = 0.f;
  #pragma unroll
  for (int i = 0; i < K; ++i) s += top[i] + bot[i];
  out[g] = s * (1.0f / K);
}

// ---------------- fallback (round-4 single kernel) if ws too small ----------
__device__ __forceinline__ void load_batch_fb(const float* __restrict__ p0, int t, float* v) {
  const float* p = p0 + (size_t)t * (64 * CH);
  #pragma unroll
  for (int u = 0; u < 32; ++u)
    v[u] = p[(size_t)(u * 2 * CH)];
}

__global__ __launch_bounds__(256, 1)
void wildcat_fallback(const float* __restrict__ x, float* __restrict__ out) {
  const int b     = blockIdx.x >> 4;
  const int cbase = (blockIdx.x & 15) << 5;
  const int w     = threadIdx.x >> 6;
  const int lane  = threadIdx.x & 63;
  const int c     = cbase + (lane & 31);
  const int rpar  = lane >> 5;

  const float* p0 = x + ((size_t)(b * NR + w * 1024 + rpar)) * CH + c;

  float top[32], bot[32], vA[32], vB[32];
  load_batch_fb(p0, 0, vA);
  load_batch_fb(p0, 1, vB);
  __builtin_amdgcn_sched_barrier(0);

  sort32_desc(vA);
  #pragma unroll
  for (int i = 0; i < 32; ++i) { top[i] = vA[i]; bot[i] = vA[31 - i]; }

  for (int tp = 0; tp < 7; ++tp) {
    load_batch_fb(p0, 2 * tp + 2, vA);
    __builtin_amdgcn_sched_barrier(0);
    sort32_desc(vB); merge_top(top, vB); merge_bot_dDesc(bot, vB);
    load_batch_fb(p0, 2 * tp + 3, vB);
    __builtin_amdgcn_sched_barrier(0);
    sort32_desc(vA); merge_top(top, vA); merge_bot_dDesc(bot, vA);
  }
  sort32_desc(vB); merge_top(top, vB); merge_bot_dDesc(bot, vB);

  {
    float pt[32], pb[32];
    #pragma unroll
    for (int i = 0; i < 32; ++i) pt[i] = __shfl_xor(top[i], 32, 64);
    #pragma unroll
    for (int i = 0; i < 32; ++i) pb[i] = __shfl_xor(bot[i], 32, 64);
    #pragma unroll
    for (int i = 0; i < 32; ++i) top[i] = fmaxf(top[i], pt[31 - i]);
    clean32_desc(top);
    #pragma unroll
    for (int i = 0; i < 32; ++i) bot[i] = fminf(bot[i], pb[31 - i]);
    clean32_asc(bot);
  }

  __shared__ float lds[2 * 32 * 64];
  #pragma unroll
  for (int half = 2; half >= 1; half >>= 1) {
    __syncthreads();
    if (w >= half && w < 2 * half && lane < 32) {
      float* dst = &lds[((w - half) * 32 + lane) * 64];
      #pragma unroll
      for (int i = 0; i < 32; ++i) { dst[i] = top[i]; dst[32 + i] = bot[i]; }
    }
    __syncthreads();
    if (w < half && lane < 32) {
      const float* src = &lds[(w * 32 + lane) * 64];
      float pt[32], pb[32];
      #pragma unroll
      for (int i = 0; i < 32; ++i) { pt[i] = src[i]; pb[i] = src[32 + i]; }
      #pragma unroll
      for (int i = 0; i < 32; ++i) top[i] = fmaxf(top[i], pt[31 - i]);
      clean32_desc(top);
      #pragma unroll
      for (int i = 0; i < 32; ++i) bot[i] = fminf(bot[i], pb[31 - i]);
      clean32_asc(bot);
    }
  }

  if (w == 0 && lane < 32) {
    float s = 0.f;
    #pragma unroll
    for (int i = 0; i < K; ++i) s += top[i] + bot[i];
    out[b * CH + cbase + lane] = s * (1.0f / K);
  }
}

extern "C" void kernel_launch(void* const* d_in, const int* in_sizes, int n_in,
                              void* d_out, int out_size, void* d_ws, size_t ws_size,
                              hipStream_t stream) {
  const float* x = (const float*)d_in[0];
  float* out = (float*)d_out;
  if (ws_size >= WS_NEED) {
    float* ws = (float*)d_ws;
    hipLaunchKernelGGL(wildcat_part1, dim3(256), dim3(512), 0, stream, x, ws);
    hipLaunchKernelGGL(wildcat_part2, dim3(64), dim3(256), 0, stream, ws, out);
  } else {
    hipLaunchKernelGGL(wildcat_fallback, dim3(512), dim3(256), 0, stream, x, out);
  }
}

// Round 7
// 83.473 us; speedup vs baseline: 1.0532x; 1.0532x over previous
//
#include <hip/hip_runtime.h>
#include <math.h>

// WildcatPool2d: x[32,64,64,512] fp32 -> out[32,512] fp32
// out[b,c] = mean(top20 over 4096 spatial) + mean(bottom20 over 4096 spatial)
//
// Round 7: occupancy fix. All 512-thread variants were silently VGPR-capped
// at 128 (8-wave block => 2 waves/EU min) and spilled; the 256-thread ones
// ran at only 2 waves/SIMD and exposed load latency (dur = mem + valu, no
// overlap). This round: batch 16 (not 32) => arrays 96 floats, peak live
// ~120 => fits the <=128 VGPR tier => 4 waves/SIMD via launch_bounds(256,4).
// 1024 blocks = 4/CU co-resident, zero tail. K2 finisher merges row-halves.

constexpr int CH = 512;
constexpr int NR = 4096;
constexpr int K  = 20;
constexpr size_t WS_NEED = (size_t)32 * 2 * 40 * CH * sizeof(float);  // 5.24 MB

__device__ __forceinline__ void ce_desc(float& a, float& b) {
  float hi = fmaxf(a, b);
  float lo = fminf(a, b);
  a = hi; b = lo;
}
__device__ __forceinline__ void ce_asc(float& a, float& b) {
  float lo = fminf(a, b);
  float hi = fmaxf(a, b);
  a = lo; b = hi;
}

// full bitonic sort of 16 registers, descending (10 levels, 80 CE)
__device__ __forceinline__ void sort16_desc(float* v) {
  #pragma unroll
  for (int k = 2; k <= 16; k <<= 1) {
    #pragma unroll
    for (int j = k >> 1; j > 0; j >>= 1) {
      #pragma unroll
      for (int i = 0; i < 16; ++i) {
        int l = i ^ j;
        if (l > i) {
          if ((i & k) == 0) ce_desc(v[i], v[l]);
          else              ce_asc(v[i], v[l]);
        }
      }
    }
  }
}
__device__ __forceinline__ void clean32_desc(float* v) {
  #pragma unroll
  for (int j = 16; j > 0; j >>= 1) {
    #pragma unroll
    for (int i = 0; i < 32; ++i) {
      int l = i ^ j;
      if (l > i) ce_desc(v[i], v[l]);
    }
  }
}
__device__ __forceinline__ void clean32_asc(float* v) {
  #pragma unroll
  for (int j = 16; j > 0; j >>= 1) {
    #pragma unroll
    for (int i = 0; i < 32; ++i) {
      int l = i ^ j;
      if (l > i) ce_asc(v[i], v[l]);
    }
  }
}

// merge desc-sorted v[16] into top[32] (desc): pad-to-32 collapses to
// 16 fmax on the upper half + clean.
__device__ __forceinline__ void merge_top16(float* top, const float* v) {
  #pragma unroll
  for (int i = 16; i < 32; ++i) top[i] = fmaxf(top[i], v[31 - i]);
  clean32_desc(top);
}
// merge desc-sorted v[16] (= asc reversed) into bot[32] (asc)
__device__ __forceinline__ void merge_bot16(float* bot, const float* v) {
  #pragma unroll
  for (int i = 16; i < 32; ++i) bot[i] = fminf(bot[i], v[i - 16]);
  clean32_asc(bot);
}
// full 32+32 merges (epilogue / K2); d desc for top, d asc for bot
__device__ __forceinline__ void merge_top32(float* top, const float* d) {
  #pragma unroll
  for (int i = 0; i < 32; ++i) top[i] = fmaxf(top[i], d[31 - i]);
  clean32_desc(top);
}
__device__ __forceinline__ void merge_bot32(float* bot, const float* d) {
  #pragma unroll
  for (int i = 0; i < 32; ++i) bot[i] = fminf(bot[i], d[31 - i]);
  clean32_asc(bot);
}

// load batch t: 16 consecutive rows starting at row 16t (row stride = CH)
__device__ __forceinline__ void load16(const float* __restrict__ p0, int t, float* v) {
  const float* p = p0 + (size_t)t * 16 * CH;
  #pragma unroll
  for (int u = 0; u < 16; ++u)
    v[u] = p[(size_t)u * CH];
}

// ---------------- K1: per-(b, chgroup, row-half) partial top20/bot20 --------
__global__ __launch_bounds__(256, 4)
void wildcat_part1(const float* __restrict__ x, float* __restrict__ ws) {
  const int lb    = blockIdx.x;          // 1024 blocks
  const int b     = lb >> 5;
  const int chg   = (lb >> 1) & 15;
  const int half  = lb & 1;
  const int w     = threadIdx.x >> 6;    // wave 0..3
  const int lane  = threadIdx.x & 63;
  const int c     = chg * 32 + (lane & 31);
  const int strip = w * 2 + (lane >> 5); // 8 strips of 256 rows in this half

  const float* p0 = x + ((size_t)b * NR + half * 2048 + strip * 256) * CH + c;

  float top[32], bot[32], vA[16], vB[16];

  load16(p0, 0, vA);
  load16(p0, 1, vB);
  __builtin_amdgcn_sched_barrier(0);

  sort16_desc(vA);
  #pragma unroll
  for (int i = 0; i < 16; ++i) {
    top[i] = vA[i];        top[16 + i] = -INFINITY;
    bot[i] = vA[15 - i];   bot[16 + i] = INFINITY;
  }

  // batches 1..14 in 7 ping-pong pairs; batch 15 in the epilogue
  #pragma unroll 1
  for (int tp = 0; tp < 7; ++tp) {
    load16(p0, 2 * tp + 2, vA);
    __builtin_amdgcn_sched_barrier(0);
    sort16_desc(vB); merge_top16(top, vB); merge_bot16(bot, vB);
    load16(p0, 2 * tp + 3, vB);
    __builtin_amdgcn_sched_barrier(0);
    sort16_desc(vA); merge_top16(top, vA); merge_bot16(bot, vA);
  }
  sort16_desc(vB); merge_top16(top, vB); merge_bot16(bot, vB);

  // intra-wave: lane l <-> l+32 merges the strip pair (same channel)
  {
    float pt[32], pb[32];
    #pragma unroll
    for (int i = 0; i < 32; ++i) pt[i] = __shfl_xor(top[i], 32, 64);
    #pragma unroll
    for (int i = 0; i < 32; ++i) pb[i] = __shfl_xor(bot[i], 32, 64);
    merge_top32(top, pt);   // pt desc
    merge_bot32(bot, pb);   // pb asc
  }

  // cross-wave tree 4 -> 2 -> 1 (stride 65 floats: conflict-free)
  __shared__ float lds[2 * 32 * 65];   // ~16.6 KB
  #pragma unroll
  for (int hw = 2; hw >= 1; hw >>= 1) {
    __syncthreads();
    if (w >= hw && w < 2 * hw && lane < 32) {
      float* dst = &lds[((w - hw) * 32 + lane) * 65];
      #pragma unroll
      for (int i = 0; i < 32; ++i) { dst[i] = top[i]; dst[32 + i] = bot[i]; }
    }
    __syncthreads();
    if (w < hw && lane < 32) {
      const float* src = &lds[(w * 32 + lane) * 65];
      float pt[32], pb[32];
      #pragma unroll
      for (int i = 0; i < 32; ++i) { pt[i] = src[i]; pb[i] = src[32 + i]; }
      merge_top32(top, pt);
      merge_bot32(bot, pb);
    }
  }

  // ws layout [b][half][j 0..39][c]: per j, 32 contiguous floats per block
  if (w == 0 && lane < 32) {
    float* wsp = ws + ((size_t)(b * 2 + half) * 40) * CH + chg * 32 + lane;
    #pragma unroll
    for (int j = 0; j < 20; ++j) wsp[(size_t)j * CH] = top[j];
    #pragma unroll
    for (int j = 0; j < 20; ++j) wsp[(size_t)(20 + j) * CH] = bot[j];
  }
}

// ---------------- K2: merge the 2 row-half runs per (b, ch) ----------------
__global__ __launch_bounds__(256, 1)
void wildcat_part2(const float* __restrict__ ws, float* __restrict__ out) {
  const int g = blockIdx.x * 256 + threadIdx.x;   // 0..16383
  const int b = g >> 9;
  const int ch = g & (CH - 1);
  const float* base = ws + ((size_t)(b * 2) * 40) * CH + ch;
  const float* base1 = base + (size_t)40 * CH;

  float top[32], bot[32], d[32];
  #pragma unroll
  for (int j = 0; j < 20; ++j) top[j] = base[(size_t)j * CH];
  #pragma unroll
  for (int j = 20; j < 32; ++j) top[j] = -INFINITY;
  #pragma unroll
  for (int j = 0; j < 20; ++j) bot[j] = base[(size_t)(20 + j) * CH];
  #pragma unroll
  for (int j = 20; j < 32; ++j) bot[j] = INFINITY;

  #pragma unroll
  for (int j = 0; j < 20; ++j) d[j] = base1[(size_t)j * CH];
  #pragma unroll
  for (int j = 20; j < 32; ++j) d[j] = -INFINITY;   // desc run, pad tail
  merge_top32(top, d);
  #pragma unroll
  for (int j = 0; j < 20; ++j) d[j] = base1[(size_t)(20 + j) * CH];
  #pragma unroll
  for (int j = 20; j < 32; ++j) d[j] = INFINITY;    // asc run, pad tail
  merge_bot32(bot, d);

  float s = 0.f;
  #pragma unroll
  for (int i = 0; i < K; ++i) s += top[i] + bot[i];
  out[g] = s * (1.0f / K);
}

// ---------------- fallback (round-4 single kernel) if ws too small ----------
__device__ __forceinline__ void sort32_desc_fb(float* v) {
  #pragma unroll
  for (int k = 2; k <= 32; k <<= 1) {
    #pragma unroll
    for (int j = k >> 1; j > 0; j >>= 1) {
      #pragma unroll
      for (int i = 0; i < 32; ++i) {
        int l = i ^ j;
        if (l > i) {
          if ((i & k) == 0) ce_desc(v[i], v[l]);
          else              ce_asc(v[i], v[l]);
        }
      }
    }
  }
}
__device__ __forceinline__ void load_batch_fb(const float* __restrict__ p0, int t, float* v) {
  const float* p = p0 + (size_t)t * (64 * CH);
  #pragma unroll
  for (int u = 0; u < 32; ++u)
    v[u] = p[(size_t)(u * 2 * CH)];
}
__device__ __forceinline__ void merge_top_fb(float* top, const float* d) {
  #pragma unroll
  for (int i = 0; i < 32; ++i) top[i] = fmaxf(top[i], d[31 - i]);
  clean32_desc(top);
}
__device__ __forceinline__ void merge_bot_fb(float* bot, const float* d) {
  #pragma unroll
  for (int i = 0; i < 32; ++i) bot[i] = fminf(bot[i], d[i]);
  clean32_asc(bot);
}

__global__ __launch_bounds__(256, 1)
void wildcat_fallback(const float* __restrict__ x, float* __restrict__ out) {
  const int b     = blockIdx.x >> 4;
  const int cbase = (blockIdx.x & 15) << 5;
  const int w     = threadIdx.x >> 6;
  const int lane  = threadIdx.x & 63;
  const int c     = cbase + (lane & 31);
  const int rpar  = lane >> 5;

  const float* p0 = x + ((size_t)(b * NR + w * 1024 + rpar)) * CH + c;

  float top[32], bot[32], vA[32], vB[32];
  load_batch_fb(p0, 0, vA);
  load_batch_fb(p0, 1, vB);
  __builtin_amdgcn_sched_barrier(0);

  sort32_desc_fb(vA);
  #pragma unroll
  for (int i = 0; i < 32; ++i) { top[i] = vA[i]; bot[i] = vA[31 - i]; }

  for (int tp = 0; tp < 7; ++tp) {
    load_batch_fb(p0, 2 * tp + 2, vA);
    __builtin_amdgcn_sched_barrier(0);
    sort32_desc_fb(vB); merge_top_fb(top, vB); merge_bot_fb(bot, vB);
    load_batch_fb(p0, 2 * tp + 3, vB);
    __builtin_amdgcn_sched_barrier(0);
    sort32_desc_fb(vA); merge_top_fb(top, vA); merge_bot_fb(bot, vA);
  }
  sort32_desc_fb(vB); merge_top_fb(top, vB); merge_bot_fb(bot, vB);

  {
    float pt[32], pb[32];
    #pragma unroll
    for (int i = 0; i < 32; ++i) pt[i] = __shfl_xor(top[i], 32, 64);
    #pragma unroll
    for (int i = 0; i < 32; ++i) pb[i] = __shfl_xor(bot[i], 32, 64);
    merge_top32(top, pt);
    merge_bot32(bot, pb);
  }

  __shared__ float lds[2 * 32 * 65];
  #pragma unroll
  for (int hw = 2; hw >= 1; hw >>= 1) {
    __syncthreads();
    if (w >= hw && w < 2 * hw && lane < 32) {
      float* dst = &lds[((w - hw) * 32 + lane) * 65];
      #pragma unroll
      for (int i = 0; i < 32; ++i) { dst[i] = top[i]; dst[32 + i] = bot[i]; }
    }
    __syncthreads();
    if (w < hw && lane < 32) {
      const float* src = &lds[(w * 32 + lane) * 65];
      float pt[32], pb[32];
      #pragma unroll
      for (int i = 0; i < 32; ++i) { pt[i] = src[i]; pb[i] = src[32 + i]; }
      merge_top32(top, pt);
      merge_bot32(bot, pb);
    }
  }

  if (w == 0 && lane < 32) {
    float s = 0.f;
    #pragma unroll
    for (int i = 0; i < K; ++i) s += top[i] + bot[i];
    out[b * CH + cbase + lane] = s * (1.0f / K);
  }
}

extern "C" void kernel_launch(void* const* d_in, const int* in_sizes, int n_in,
                              void* d_out, int out_size, void* d_ws, size_t ws_size,
                              hipStream_t stream) {
  const float* x = (const float*)d_in[0];
  float* out = (float*)d_out;
  if (ws_size >= WS_NEED) {
    float* ws = (float*)d_ws;
    // 1024 blocks x 256 thr = 4 blocks/CU co-resident (VGPR<=128), zero tail
    hipLaunchKernelGGL(wildcat_part1, dim3(1024), dim3(256), 0, stream, x, ws);
    hipLaunchKernelGGL(wildcat_part2, dim3(64), dim3(256), 0, stream, ws, out);
  } else {
    hipLaunchKernelGGL(wildcat_fallback, dim3(512), dim3(256), 0, stream, x, out);
  }
}

// Round 8
// 73.859 us; speedup vs baseline: 1.1903x; 1.1302x over previous
//
#include <hip/hip_runtime.h>
#include <math.h>

// WildcatPool2d: x[32,64,64,512] fp32 -> out[32,512] fp32
// out[b,c] = mean(top20 over 4096 spatial) + mean(bottom20 over 4096 spatial)
//
// Round 8: clean TLP test. All prior 4-wave/SIMD attempts were confounded by
// VGPR spills or extra VALU. Here: R4's exact batch-32 math, single-buffered
// v[32] (TLP hides latency, not ILP), in-place epilogue merges (no pt/pb
// arrays) -> ~112 peak live regs, fits the 128-VGPR tier. 512-thr blocks,
// grid 512 = 2 blocks/CU = 4 waves/SIMD, zero tail, single kernel.

constexpr int CH = 512;
constexpr int NR = 4096;
constexpr int K  = 20;

__device__ __forceinline__ void ce_desc(float& a, float& b) {
  float hi = fmaxf(a, b);
  float lo = fminf(a, b);
  a = hi; b = lo;
}
__device__ __forceinline__ void ce_asc(float& a, float& b) {
  float lo = fminf(a, b);
  float hi = fmaxf(a, b);
  a = lo; b = hi;
}

// full bitonic sort of 32 registers, descending (240 CE)
__device__ __forceinline__ void sort32_desc(float* v) {
  #pragma unroll
  for (int k = 2; k <= 32; k <<= 1) {
    #pragma unroll
    for (int j = k >> 1; j > 0; j >>= 1) {
      #pragma unroll
      for (int i = 0; i < 32; ++i) {
        int l = i ^ j;
        if (l > i) {
          if ((i & k) == 0) ce_desc(v[i], v[l]);
          else              ce_asc(v[i], v[l]);
        }
      }
    }
  }
}
__device__ __forceinline__ void clean32_desc(float* v) {
  #pragma unroll
  for (int j = 16; j > 0; j >>= 1) {
    #pragma unroll
    for (int i = 0; i < 32; ++i) {
      int l = i ^ j;
      if (l > i) ce_desc(v[i], v[l]);
    }
  }
}
__device__ __forceinline__ void clean32_asc(float* v) {
  #pragma unroll
  for (int j = 16; j > 0; j >>= 1) {
    #pragma unroll
    for (int i = 0; i < 32; ++i) {
      int l = i ^ j;
      if (l > i) ce_asc(v[i], v[l]);
    }
  }
}
// top desc(32) + d desc(32): keep 32 largest
__device__ __forceinline__ void merge_top32(float* top, const float* d) {
  #pragma unroll
  for (int i = 0; i < 32; ++i) top[i] = fmaxf(top[i], d[31 - i]);
  clean32_desc(top);
}
// bot asc(32) + d DESC(32): keep 32 smallest  (d[i] = asc-reversed[31-i])
__device__ __forceinline__ void merge_bot32_dDesc(float* bot, const float* d) {
  #pragma unroll
  for (int i = 0; i < 32; ++i) bot[i] = fminf(bot[i], d[i]);
  clean32_asc(bot);
}

__global__ __launch_bounds__(512, 4)
void wildcat_topk_kernel(const float* __restrict__ x, float* __restrict__ out) {
  const int b     = blockIdx.x >> 4;        // 32 batches
  const int chg   = blockIdx.x & 15;        // 16 channel groups of 32
  const int w     = threadIdx.x >> 6;       // wave 0..7
  const int lane  = threadIdx.x & 63;
  const int c     = chg * 32 + (lane & 31);
  const int strip = w * 2 + (lane >> 5);    // 16 strips of 256 rows

  const float* p0 = x + ((size_t)b * NR + (size_t)strip * 256) * CH + c;

  float top[32], bot[32], v[32];

  // batch 0 initializes top/bot directly
  #pragma unroll
  for (int u = 0; u < 32; ++u) v[u] = p0[(size_t)u * CH];
  sort32_desc(v);
  #pragma unroll
  for (int i = 0; i < 32; ++i) { top[i] = v[i]; bot[i] = v[31 - i]; }

  // batches 1..7 (single-buffered; TLP at 4 waves/SIMD hides load latency)
  #pragma unroll 1
  for (int t = 1; t < 8; ++t) {
    const float* p = p0 + (size_t)t * 32 * CH;
    #pragma unroll
    for (int u = 0; u < 32; ++u) v[u] = p[(size_t)u * CH];
    sort32_desc(v);
    merge_top32(top, v);
    merge_bot32_dDesc(bot, v);
  }

  // --- intra-wave merge: lane l <-> l+32 (strip pair), in-place, 2 temps ---
  #pragma unroll
  for (int i = 0; i < 16; ++i) {
    float a  = __shfl_xor(top[31 - i], 32, 64);   // partner B[31-i]
    float bb = __shfl_xor(top[i], 32, 64);        // partner B[i]
    top[i]      = fmaxf(top[i], a);
    top[31 - i] = fmaxf(top[31 - i], bb);
  }
  clean32_desc(top);
  #pragma unroll
  for (int i = 0; i < 16; ++i) {
    float a  = __shfl_xor(bot[31 - i], 32, 64);
    float bb = __shfl_xor(bot[i], 32, 64);
    bot[i]      = fminf(bot[i], a);
    bot[31 - i] = fminf(bot[31 - i], bb);
  }
  clean32_asc(bot);

  // --- cross-wave tree 8 -> 4 -> 2 -> 1 (stride 65: conflict-free) ---
  __shared__ float lds[4 * 32 * 65];   // 33.3 KB
  #pragma unroll
  for (int hw = 4; hw >= 1; hw >>= 1) {
    __syncthreads();
    if (w >= hw && w < 2 * hw && lane < 32) {
      float* dst = &lds[((w - hw) * 32 + lane) * 65];
      #pragma unroll
      for (int i = 0; i < 32; ++i) { dst[i] = top[i]; dst[32 + i] = bot[i]; }
    }
    __syncthreads();
    if (w < hw && lane < 32) {
      const float* src = &lds[(w * 32 + lane) * 65];
      #pragma unroll
      for (int i = 0; i < 16; ++i) {
        float a = src[31 - i], bb = src[i];
        top[i]      = fmaxf(top[i], a);
        top[31 - i] = fmaxf(top[31 - i], bb);
      }
      clean32_desc(top);
      #pragma unroll
      for (int i = 0; i < 16; ++i) {
        float a = src[32 + 31 - i], bb = src[32 + i];
        bot[i]      = fminf(bot[i], a);
        bot[31 - i] = fminf(bot[31 - i], bb);
      }
      clean32_asc(bot);
    }
  }

  if (w == 0 && lane < 32) {
    float s = 0.f;
    #pragma unroll
    for (int i = 0; i < K; ++i) s += top[i] + bot[i];
    out[(size_t)b * CH + chg * 32 + lane] = s * (1.0f / K);
  }
}

extern "C" void kernel_launch(void* const* d_in, const int* in_sizes, int n_in,
                              void* d_out, int out_size, void* d_ws, size_t ws_size,
                              hipStream_t stream) {
  const float* x = (const float*)d_in[0];
  float* out = (float*)d_out;
  // 512 blocks x 512 threads = 2 blocks/CU = 4 waves/SIMD, all co-resident
  hipLaunchKernelGGL(wildcat_topk_kernel, dim3(512), dim3(512), 0, stream, x, out);
}